// Round 1
// baseline (1428.177 us; speedup 1.0000x reference)
//
#include <hip/hip_runtime.h>
#include <math.h>

// Problem constants
#define BB   64
#define CIN  16
#define LL   8192
#define CO   32
#define TCO  64
constexpr int T0n = 128;   // frames for n=64
constexpr int T1n = 32;    // frames for n=256
constexpr int F0n = 33;
constexpr int F1n = 129;

typedef unsigned int   uint32;
typedef unsigned short u16;
typedef __attribute__((ext_vector_type(8))) _Float16 half8;  // 8 f16 (4 VGPRs)
typedef __attribute__((ext_vector_type(4))) float    f32x4;  // MFMA accumulator

// ---------------- STFT: real-input DFT, k<->n-k pairing, rotation recurrence ----
// p layout: [b][t][c][f] (float2 = re,im)
template<int N, int F, int TCH, int TFR>
__global__ __launch_bounds__(256)
void stft_kernel(const float* __restrict__ x, float2* __restrict__ p) {
    constexpr int NCH  = TFR / TCH;
    constexpr int SPAN = N * TCH;          // 512 for both configs
    static_assert(SPAN == 512, "span");
    __shared__ float  xs[SPAN];
    __shared__ float2 uv[TCH][N / 2];      // (u,v), k=1..N/2-1
    __shared__ float2 edge[TCH];           // (x[0], x[N/2])
    int bid   = blockIdx.x;
    int chunk = bid % NCH;
    int bc    = bid / NCH;                 // b*CIN + c
    const float* xrow = x + (size_t)bc * LL;
    int g0 = chunk * SPAN - N / 2;
    for (int i = threadIdx.x; i < SPAN; i += 256) {
        int gi = g0 + i; gi = gi < 0 ? -gi : gi;   // reflect (left edge only)
        xs[i] = xrow[gi];
    }
    __syncthreads();
    for (int i = threadIdx.x; i < TCH * (N / 2); i += 256) {
        int fl = i / (N / 2), k = i % (N / 2);
        float a = xs[fl * N + k];
        if (k == 0) {
            edge[fl] = make_float2(a, xs[fl * N + N / 2]);
        } else {
            float b2 = xs[fl * N + N - k];
            uv[fl][k] = make_float2(a + b2, a - b2);
        }
    }
    __syncthreads();
    int c = bc % CIN, b = bc / CIN;
    for (int j = threadIdx.x; j < TCH * F; j += 256) {
        int fl = j / F, f = j - fl * F;
        float2 e = edge[fl];
        float re = e.x + ((f & 1) ? -e.y : e.y);
        float im = 0.f;
        float s1, c1;
        sincosf(6.28318530717958647692f * (float)f / (float)N, &s1, &c1);
        float cc = c1, ss = s1;            // angle = 2*pi*f*k/N at k=1
        #pragma unroll 4
        for (int k = 1; k < N / 2; ++k) {
            float2 w = uv[fl][k];
            re = fmaf(w.x, cc, re);        // + u*cos
            im = fmaf(-w.y, ss, im);       // - v*sin
            float cn = fmaf(cc, c1, -ss * s1);
            ss = fmaf(cc, s1, ss * c1);
            cc = cn;
        }
        int t = chunk * TCH + fl;
        p[(((size_t)b * TFR + t) * CIN + c) * F + f] = make_float2(re, im);
    }
}

// ---------------- merge (attention over 4 sub-frames), in-place into p1 --------
__global__ __launch_bounds__(256)
void merge_kernel(const float2* __restrict__ p0, float2* __restrict__ p1,
                  const float* __restrict__ mkr, const float* __restrict__ mki,
                  const float* __restrict__ mbr, const float* __restrict__ mbi) {
    int idx = blockIdx.x * 256 + threadIdx.x;
    const int total = BB * T1n * CIN * F0n;
    if (idx >= total) return;
    int f0 = idx % F0n; int r1 = idx / F0n;
    int c  = r1 % CIN;  int r2 = r1 / CIN;
    int t1 = r2 % T1n;  int b  = r2 / T1n;
    float2 pm[4];
    #pragma unroll
    for (int r = 0; r < 4; ++r) {
        int t = t1 * 4 + r;
        pm[r] = p0[(((size_t)b * T0n + t) * CIN + c) * F0n + f0];
    }
    float mag[4], mx = -1e30f;
    #pragma unroll
    for (int s = 0; s < 4; ++s) {
        float atr = mbr[s], ati = mbi[s];
        #pragma unroll
        for (int r = 0; r < 4; ++r) {
            float kr = mkr[r * 4 + s], ki = mki[r * 4 + s];
            atr = fmaf(pm[r].x, kr, atr); atr = fmaf(-pm[r].y, ki, atr);
            ati = fmaf(pm[r].x, ki, ati); ati = fmaf(pm[r].y, kr, ati);
        }
        mag[s] = sqrtf(atr * atr + ati * ati);
        mx = fmaxf(mx, mag[s]);
    }
    float se = 0.f;
    #pragma unroll
    for (int s = 0; s < 4; ++s) { mag[s] = expf(mag[s] - mx); se += mag[s]; }
    float inv = 4.0f / se;                 // RATIO / sum
    float mr = 0.f, mi = 0.f;
    #pragma unroll
    for (int r = 0; r < 4; ++r) { mr = fmaf(pm[r].x, mag[r], mr); mi = fmaf(pm[r].y, mag[r], mi); }
    p1[(((size_t)b * T1n + t1) * CIN + c) * F1n + 4 * f0] = make_float2(mr * inv, mi * inv);
}

// ---------------- complex batch-norm stats -> per-batch affine ------------------
__global__ __launch_bounds__(256)
void cbn_kernel(const float2* __restrict__ p0, const float2* __restrict__ p1,
                const float* __restrict__ gamma, const float* __restrict__ beta,
                float4* __restrict__ bn) {
    int head = blockIdx.x >> 6;
    int b    = blockIdx.x & 63;
    int Nel  = head ? (T1n * CIN * F1n) : (T0n * CIN * F0n);
    const float2* base = head ? (p1 + (size_t)b * (T1n * CIN * F1n))
                              : (p0 + (size_t)b * (T0n * CIN * F0n));
    float sr = 0.f, si = 0.f, s2 = 0.f;
    for (int i = threadIdx.x; i < Nel; i += 256) {
        float2 v = base[i];
        sr += v.x; si += v.y;
        s2 = fmaf(v.x, v.x, s2); s2 = fmaf(v.y, v.y, s2);
    }
    __shared__ float red[3][256];
    red[0][threadIdx.x] = sr; red[1][threadIdx.x] = si; red[2][threadIdx.x] = s2;
    __syncthreads();
    for (int off = 128; off > 0; off >>= 1) {
        if (threadIdx.x < off) {
            red[0][threadIdx.x] += red[0][threadIdx.x + off];
            red[1][threadIdx.x] += red[1][threadIdx.x + off];
            red[2][threadIdx.x] += red[2][threadIdx.x + off];
        }
        __syncthreads();
    }
    if (threadIdx.x == 0) {
        float invN = 1.f / (float)Nel;
        float mur = red[0][0] * invN, mui = red[1][0] * invN;
        float var = red[2][0] * invN - mur * mur - mui * mui;
        float g = gamma[head * BB + b] * rsqrtf(var + 1e-5f);
        bn[head * BB + b] = make_float4(g, beta[head * BB + b] - mur * g, -mui * g, 0.f);
    }
}

// ---------------- init: irfft twiddle matrix, A-fragment order, split fp16 -----
// W[m][k2]: k2=2f -> scale_f*cos(2*pi*m*f/N); k2=2f+1 -> -scale_f*sin(...)
// W scaled by 2^10; S scaled by 2^5; epilogue multiplies by 2^-15.
// frag idx = ((mtile*KT + kt)*64 + lane)*8 + j ; m = mtile*16+(lane&15),
// k2 = kt*32 + (lane>>4)*8 + j.  sin(0)=0 zeroes DC/Nyquist imag (numpy irfft).
__global__ __launch_bounds__(256)
void init_w_kernel(u16* __restrict__ whi0, u16* __restrict__ wlo0,
                   u16* __restrict__ whi1, u16* __restrict__ wlo1) {
    int idx = blockIdx.x * 256 + threadIdx.x;
    int N, F, KT, id; u16 *dh, *dl;
    if (idx < 6144)              { N = 64;  F = F0n; KT = 3; dh = whi0; dl = wlo0; id = idx; }
    else if (idx < 6144 + 73728) { N = 256; F = F1n; KT = 9; dh = whi1; dl = wlo1; id = idx - 6144; }
    else return;
    int j    = id & 7;
    int lane = (id >> 3) & 63;
    int rest = id >> 9;
    int kt   = rest % KT;
    int mt   = rest / KT;
    int m  = mt * 16 + (lane & 15);
    int k2 = kt * 32 + (lane >> 4) * 8 + j;
    float v = 0.f;
    if (k2 < 2 * F) {
        int f = k2 >> 1;
        double scale = (f == 0 || f == F - 1) ? (1024.0 / N) : (2048.0 / N);
        int u = (m * f) % N;
        double th = 6.283185307179586476925286766559 * (double)u / (double)N;
        v = (float)((k2 & 1) ? (-scale * sin(th)) : (scale * cos(th)));
    }
    _Float16 h = (_Float16)v;
    _Float16 l = (_Float16)(v - (float)h);
    dh[id] = *(u16*)&h;
    dl[id] = *(u16*)&l;
}

// ---------------- init: fk tables repacked coalesced + per-(f,o) ci-sum --------
// fkq layout: [c2][f*32+o] float4 = (kr[2c2], ki[2c2], kr[2c2+1], ki[2c2+1])
//   -> einsum load at lane-consecutive i = f*32+o is fully coalesced (16B stride).
// fks layout: [f*32+o] float2 = sum_ci (kr, ki)  (folds the CBN beta/mu offset).
__global__ __launch_bounds__(256)
void init_fk_kernel(const float* __restrict__ r0, const float* __restrict__ i0,
                    const float* __restrict__ r1, const float* __restrict__ i1,
                    float4* __restrict__ q0, float4* __restrict__ q1,
                    float2* __restrict__ s0, float2* __restrict__ s1) {
    int idx = blockIdx.x * 256 + threadIdx.x;
    constexpr int NQ0 = 8 * F0n * 32;   // 8448
    constexpr int NQ1 = 8 * F1n * 32;   // 33024
    constexpr int NS0 = F0n * 32;       // 1056
    constexpr int NS1 = F1n * 32;       // 4128
    if (idx < NQ0) {
        int id = idx;
        int c2 = id / (F0n * 32); int rem = id % (F0n * 32);
        int f = rem >> 5, o = rem & 31;
        int s = (f * CIN + 2 * c2) * CO + o;
        q0[id] = make_float4(r0[s], i0[s], r0[s + CO], i0[s + CO]);
    } else if (idx < NQ0 + NQ1) {
        int id = idx - NQ0;
        int c2 = id / (F1n * 32); int rem = id % (F1n * 32);
        int f = rem >> 5, o = rem & 31;
        int s = (f * CIN + 2 * c2) * CO + o;
        q1[id] = make_float4(r1[s], i1[s], r1[s + CO], i1[s + CO]);
    } else if (idx < NQ0 + NQ1 + NS0) {
        int id = idx - NQ0 - NQ1;
        int f = id >> 5, o = id & 31;
        float sr = 0.f, si = 0.f;
        for (int ci = 0; ci < CIN; ++ci) {
            int s = (f * CIN + ci) * CO + o;
            sr += r0[s]; si += i0[s];
        }
        s0[id] = make_float2(sr, si);
    } else if (idx < NQ0 + NQ1 + NS0 + NS1) {
        int id = idx - NQ0 - NQ1 - NS0;
        int f = id >> 5, o = id & 31;
        float sr = 0.f, si = 0.f;
        for (int ci = 0; ci < CIN; ++ci) {
            int s = (f * CIN + ci) * CO + o;
            sr += r1[s]; si += i1[s];
        }
        s1[id] = make_float2(sr, si);
    }
}

// ---------------- fused CBN-apply + einsum(fp32) + irfft(split-fp16 MFMA) ------
// grid: B*(TFR+1); frame TFR re-uses spectrum of frame 0 (wrap frame)
// LDS: Shi/Slo only (37.9KB for N=256 -> 4 blocks/CU). The raw frame is staged
// into the SAME LDS (scratch overlay); einsum results transit through a
// statically-indexed register stash so no xbn buffer is needed.
// CBN affine folded: S = g * sum_ci p (x) fk  +  (t_re + i t_im) (x) fksum.
template<int N, int F, int TFR, int CH0, int KT, int KPAD>
__global__ __launch_bounds__(256, 4)
void istft_kernel(const float2* __restrict__ p,
                  const u16* __restrict__ whi, const u16* __restrict__ wlo,
                  const float4* __restrict__ fkq, const float2* __restrict__ fks,
                  const float4* __restrict__ bn,
                  const float* __restrict__ pbias, float* __restrict__ out) {
    constexpr int MTW = N / 64;            // M-tiles per wave (1 or 4)
    constexpr int FCO = F * CO;
    constexpr int QN  = (FCO + 255) / 256; // outputs per thread (stash size)
    __shared__ __align__(16) u16 smem[2][32][KPAD];
    auto& Shi = smem[0];                   // [o][k2] f16 hi (x32 scale)
    auto& Slo = smem[1];                   // [o][k2] f16 lo (residual)
    float2* xs = (float2*)&smem[0][0][0];  // scratch overlay (dead before phase 3)

    int t  = blockIdx.x % (TFR + 1);
    int b  = blockIdx.x / (TFR + 1);
    int tf = (t == TFR) ? 0 : t;
    float4 par = bn[(CH0 ? 1 : 0) * BB + b];   // (g, t_re, t_im, -)
    const float2* acc = p + ((size_t)b * TFR + tf) * CIN * F;

    // phase 1: coalesced raw-frame load into LDS scratch
    {
        const float4* a4 = (const float4*)acc;
        float4* x4 = (float4*)xs;
        for (int i = threadIdx.x; i < CIN * F / 2; i += 256) x4[i] = a4[i];
    }
    __syncthreads();

    // phase 2: einsum -> register stash (all indices compile-time after unroll)
    uint32 rhi[QN], rlo[QN];
    #pragma unroll
    for (int q = 0; q < QN; ++q) {
        int i = threadIdx.x + q * 256;
        if (i < FCO) {
            int f = i >> 5;
            float re = 0.f, im = 0.f;
            #pragma unroll
            for (int c2 = 0; c2 < 8; ++c2) {
                float4 kk = fkq[c2 * FCO + i];          // coalesced (16B stride)
                float2 xa = xs[(2 * c2) * F + f];       // LDS broadcast
                float2 xb = xs[(2 * c2 + 1) * F + f];
                re = fmaf(xa.x, kk.x, re); re = fmaf(-xa.y, kk.y, re);
                im = fmaf(xa.x, kk.y, im); im = fmaf(xa.y, kk.x, im);
                re = fmaf(xb.x, kk.z, re); re = fmaf(-xb.y, kk.w, re);
                im = fmaf(xb.x, kk.w, im); im = fmaf(xb.y, kk.z, im);
            }
            float2 fv = fks[i];
            float res = fmaf(par.x, re, fmaf(par.y, fv.x, -par.z * fv.y)) * 32.f;
            float ims = fmaf(par.x, im, fmaf(par.y, fv.y,  par.z * fv.x)) * 32.f;
            _Float16 rh = (_Float16)res; _Float16 rl = (_Float16)(res - (float)rh);
            _Float16 ih = (_Float16)ims; _Float16 il = (_Float16)(ims - (float)ih);
            rhi[q] = ((uint32)(*(u16*)&ih) << 16) | (uint32)(*(u16*)&rh);
            rlo[q] = ((uint32)(*(u16*)&il) << 16) | (uint32)(*(u16*)&rl);
        }
    }
    __syncthreads();                        // scratch reads done -> safe to overwrite

    // phase 3: spill stash to S arrays + zero-pad K tail [F, KT*16) dwords
    #pragma unroll
    for (int q = 0; q < QN; ++q) {
        int i = threadIdx.x + q * 256;
        if (i < FCO) {
            int f = i >> 5, o = i & 31;
            ((uint32*)&Shi[o][0])[f] = rhi[q];
            ((uint32*)&Slo[o][0])[f] = rlo[q];
        }
    }
    for (int i = threadIdx.x; i < 32 * (KT * 16 - F); i += 256) {
        constexpr int cols = KT * 16 - F;
        int o = i / cols, j = i - o * cols;
        ((uint32*)&Shi[o][0])[F + j] = 0;
        ((uint32*)&Slo[o][0])[F + j] = 0;
    }
    __syncthreads();

    // phase 4: MFMA.  out[k][ch] = sum_k2 W[k][k2]*S[k2][ch],
    // W*S ~ Wh*Sh + Wh*Sl + Wl*Sh.  All 8 W global loads batched per kt.
    int lane = threadIdx.x & 63, wave = threadIdx.x >> 6;
    int col = lane & 15, quad = lane >> 4;
    f32x4 accv[MTW][2];
    #pragma unroll
    for (int mt = 0; mt < MTW; ++mt)
        #pragma unroll
        for (int nt = 0; nt < 2; ++nt) {
            f32x4 z = {0.f, 0.f, 0.f, 0.f};
            accv[mt][nt] = z;
        }
    for (int kt = 0; kt < KT; ++kt) {
        half8 wah[MTW], wal[MTW];
        #pragma unroll
        for (int mt = 0; mt < MTW; ++mt) {
            int mtile = wave * MTW + mt;
            wah[mt] = ((const half8*)whi)[(mtile * KT + kt) * 64 + lane];
            wal[mt] = ((const half8*)wlo)[(mtile * KT + kt) * 64 + lane];
        }
        half8 bh0 = *(const half8*)&Shi[col][kt * 32 + quad * 8];
        half8 bh1 = *(const half8*)&Shi[16 + col][kt * 32 + quad * 8];
        half8 bl0 = *(const half8*)&Slo[col][kt * 32 + quad * 8];
        half8 bl1 = *(const half8*)&Slo[16 + col][kt * 32 + quad * 8];
        #pragma unroll
        for (int mt = 0; mt < MTW; ++mt) {
            accv[mt][0] = __builtin_amdgcn_mfma_f32_16x16x32_f16(wah[mt], bh0, accv[mt][0], 0, 0, 0);
            accv[mt][0] = __builtin_amdgcn_mfma_f32_16x16x32_f16(wah[mt], bl0, accv[mt][0], 0, 0, 0);
            accv[mt][0] = __builtin_amdgcn_mfma_f32_16x16x32_f16(wal[mt], bh0, accv[mt][0], 0, 0, 0);
            accv[mt][1] = __builtin_amdgcn_mfma_f32_16x16x32_f16(wah[mt], bh1, accv[mt][1], 0, 0, 0);
            accv[mt][1] = __builtin_amdgcn_mfma_f32_16x16x32_f16(wah[mt], bl1, accv[mt][1], 0, 0, 0);
            accv[mt][1] = __builtin_amdgcn_mfma_f32_16x16x32_f16(wal[mt], bh1, accv[mt][1], 0, 0, 0);
        }
    }
    // epilogue: row = quad*4+reg (4 consecutive l), col = ch within ntile
    constexpr float UNSCALE = 1.0f / 32768.0f;   // 2^-15 (W*2^10, S*2^5)
    size_t bb = (size_t)b * TCO;
    #pragma unroll
    for (int mt = 0; mt < MTW; ++mt) {
        int l0 = t * N + (wave * MTW + mt) * 16 + quad * 4 - N / 2;
        if ((unsigned)l0 < LL) {
            #pragma unroll
            for (int nt = 0; nt < 2; ++nt) {
                int ch = CH0 + nt * 16 + col;
                float pb = pbias[ch];
                f32x4 a = accv[mt][nt];
                float4 v;
                v.x = fmaxf(fmaf(a[0], UNSCALE, pb), 0.f);
                v.y = fmaxf(fmaf(a[1], UNSCALE, pb), 0.f);
                v.z = fmaxf(fmaf(a[2], UNSCALE, pb), 0.f);
                v.w = fmaxf(fmaf(a[3], UNSCALE, pb), 0.f);
                *(float4*)(out + (bb + ch) * LL + l0) = v;
            }
        }
    }
}

extern "C" void kernel_launch(void* const* d_in, const int* in_sizes, int n_in,
                              void* d_out, int out_size, void* d_ws, size_t ws_size,
                              hipStream_t stream) {
    const float* x     = (const float*)d_in[0];
    const float* gam   = (const float*)d_in[1];
    const float* bet   = (const float*)d_in[2];
    const float* mkr   = (const float*)d_in[3];
    const float* mki   = (const float*)d_in[4];
    const float* mbr   = (const float*)d_in[5];
    const float* mbi   = (const float*)d_in[6];
    const float* fk0r  = (const float*)d_in[7];
    const float* fk0i  = (const float*)d_in[8];
    const float* fk1r  = (const float*)d_in[9];
    const float* fk1i  = (const float*)d_in[10];
    const float* pbias = (const float*)d_in[11];
    float* out = (float*)d_out;

    float2* p0   = (float2*)d_ws;                                   // 34.6 MB
    float2* p1   = p0 + (size_t)BB * T0n * CIN * F0n;               // 33.8 MB
    float4* bnp  = (float4*)(p1 + (size_t)BB * T1n * CIN * F1n);    // 2 KB
    u16*    whi0 = (u16*)(bnp + 2 * BB);                            // 12 KB
    u16*    wlo0 = whi0 + 6144;
    u16*    whi1 = wlo0 + 6144;                                     // 144 KB
    u16*    wlo1 = whi1 + 73728;
    float4* fkq0 = (float4*)(wlo1 + 73728);                         // 132 KB
    float4* fkq1 = fkq0 + 8 * F0n * 32;                             // 516 KB
    float2* fks0 = (float2*)(fkq1 + 8 * F1n * 32);                  // 8 KB
    float2* fks1 = fks0 + F0n * 32;                                 // 33 KB

    init_w_kernel<<<(6144 + 73728 + 255) / 256, 256, 0, stream>>>(whi0, wlo0, whi1, wlo1);
    init_fk_kernel<<<(8 * (F0n + F1n) * 32 + (F0n + F1n) * 32 + 255) / 256, 256, 0, stream>>>(
        fk0r, fk0i, fk1r, fk1i, fkq0, fkq1, fks0, fks1);
    stft_kernel<64, 33, 8, 128><<<BB * CIN * 16, 256, 0, stream>>>(x, p0);
    stft_kernel<256, 129, 2, 32><<<BB * CIN * 16, 256, 0, stream>>>(x, p1);
    merge_kernel<<<(BB * T1n * CIN * F0n) / 256, 256, 0, stream>>>(p0, p1, mkr, mki, mbr, mbi);
    cbn_kernel<<<128, 256, 0, stream>>>(p0, p1, gam, bet, bnp);
    istft_kernel<64, 33, 128, 0, 3, 104><<<BB * (T0n + 1), 256, 0, stream>>>(
        p0, whi0, wlo0, fkq0, fks0, bnp, pbias, out);
    istft_kernel<256, 129, 32, 32, 9, 296><<<BB * (T1n + 1), 256, 0, stream>>>(
        p1, whi1, wlo1, fkq1, fks1, bnp, pbias, out);
}

// Round 2
// 567.064 us; speedup vs baseline: 2.5185x; 2.5185x over previous
//
#include <hip/hip_runtime.h>
#include <math.h>

// Problem constants
#define BB   64
#define CIN  16
#define LL   8192
#define CO   32
#define TCO  64
constexpr int T0n = 128;   // frames for n=64
constexpr int T1n = 32;    // frames for n=256
constexpr int F0n = 33;
constexpr int F1n = 129;

typedef unsigned int   uint32;
typedef unsigned short u16;
typedef __attribute__((ext_vector_type(8))) _Float16 half8;  // 8 f16 (4 VGPRs)
typedef __attribute__((ext_vector_type(4))) float    f32x4;  // MFMA accumulator

// ---------------- STFT: real-input DFT, k<->n-k pairing, rotation recurrence ----
// p layout: [b][t][c][f] (float2 = re,im)
template<int N, int F, int TCH, int TFR>
__global__ __launch_bounds__(256)
void stft_kernel(const float* __restrict__ x, float2* __restrict__ p) {
    constexpr int NCH  = TFR / TCH;
    constexpr int SPAN = N * TCH;          // 512 for both configs
    static_assert(SPAN == 512, "span");
    __shared__ float  xs[SPAN];
    __shared__ float2 uv[TCH][N / 2];      // (u,v), k=1..N/2-1
    __shared__ float2 edge[TCH];           // (x[0], x[N/2])
    int bid   = blockIdx.x;
    int chunk = bid % NCH;
    int bc    = bid / NCH;                 // b*CIN + c
    const float* xrow = x + (size_t)bc * LL;
    int g0 = chunk * SPAN - N / 2;
    for (int i = threadIdx.x; i < SPAN; i += 256) {
        int gi = g0 + i; gi = gi < 0 ? -gi : gi;   // reflect (left edge only)
        xs[i] = xrow[gi];
    }
    __syncthreads();
    for (int i = threadIdx.x; i < TCH * (N / 2); i += 256) {
        int fl = i / (N / 2), k = i % (N / 2);
        float a = xs[fl * N + k];
        if (k == 0) {
            edge[fl] = make_float2(a, xs[fl * N + N / 2]);
        } else {
            float b2 = xs[fl * N + N - k];
            uv[fl][k] = make_float2(a + b2, a - b2);
        }
    }
    __syncthreads();
    int c = bc % CIN, b = bc / CIN;
    for (int j = threadIdx.x; j < TCH * F; j += 256) {
        int fl = j / F, f = j - fl * F;
        float2 e = edge[fl];
        float re = e.x + ((f & 1) ? -e.y : e.y);
        float im = 0.f;
        float s1, c1;
        sincosf(6.28318530717958647692f * (float)f / (float)N, &s1, &c1);
        float cc = c1, ss = s1;            // angle = 2*pi*f*k/N at k=1
        #pragma unroll 4
        for (int k = 1; k < N / 2; ++k) {
            float2 w = uv[fl][k];
            re = fmaf(w.x, cc, re);        // + u*cos
            im = fmaf(-w.y, ss, im);       // - v*sin
            float cn = fmaf(cc, c1, -ss * s1);
            ss = fmaf(cc, s1, ss * c1);
            cc = cn;
        }
        int t = chunk * TCH + fl;
        p[(((size_t)b * TFR + t) * CIN + c) * F + f] = make_float2(re, im);
    }
}

// ---------------- merge (attention over 4 sub-frames), in-place into p1 --------
__global__ __launch_bounds__(256)
void merge_kernel(const float2* __restrict__ p0, float2* __restrict__ p1,
                  const float* __restrict__ mkr, const float* __restrict__ mki,
                  const float* __restrict__ mbr, const float* __restrict__ mbi) {
    int idx = blockIdx.x * 256 + threadIdx.x;
    const int total = BB * T1n * CIN * F0n;
    if (idx >= total) return;
    int f0 = idx % F0n; int r1 = idx / F0n;
    int c  = r1 % CIN;  int r2 = r1 / CIN;
    int t1 = r2 % T1n;  int b  = r2 / T1n;
    float2 pm[4];
    #pragma unroll
    for (int r = 0; r < 4; ++r) {
        int t = t1 * 4 + r;
        pm[r] = p0[(((size_t)b * T0n + t) * CIN + c) * F0n + f0];
    }
    float mag[4], mx = -1e30f;
    #pragma unroll
    for (int s = 0; s < 4; ++s) {
        float atr = mbr[s], ati = mbi[s];
        #pragma unroll
        for (int r = 0; r < 4; ++r) {
            float kr = mkr[r * 4 + s], ki = mki[r * 4 + s];
            atr = fmaf(pm[r].x, kr, atr); atr = fmaf(-pm[r].y, ki, atr);
            ati = fmaf(pm[r].x, ki, ati); ati = fmaf(pm[r].y, kr, ati);
        }
        mag[s] = sqrtf(atr * atr + ati * ati);
        mx = fmaxf(mx, mag[s]);
    }
    float se = 0.f;
    #pragma unroll
    for (int s = 0; s < 4; ++s) { mag[s] = expf(mag[s] - mx); se += mag[s]; }
    float inv = 4.0f / se;                 // RATIO / sum
    float mr = 0.f, mi = 0.f;
    #pragma unroll
    for (int r = 0; r < 4; ++r) { mr = fmaf(pm[r].x, mag[r], mr); mi = fmaf(pm[r].y, mag[r], mi); }
    p1[(((size_t)b * T1n + t1) * CIN + c) * F1n + 4 * f0] = make_float2(mr * inv, mi * inv);
}

// ---------------- complex batch-norm stats -> per-batch affine ------------------
__global__ __launch_bounds__(256)
void cbn_kernel(const float2* __restrict__ p0, const float2* __restrict__ p1,
                const float* __restrict__ gamma, const float* __restrict__ beta,
                float4* __restrict__ bn) {
    int head = blockIdx.x >> 6;
    int b    = blockIdx.x & 63;
    int Nel  = head ? (T1n * CIN * F1n) : (T0n * CIN * F0n);
    const float2* base = head ? (p1 + (size_t)b * (T1n * CIN * F1n))
                              : (p0 + (size_t)b * (T0n * CIN * F0n));
    float sr = 0.f, si = 0.f, s2 = 0.f;
    for (int i = threadIdx.x; i < Nel; i += 256) {
        float2 v = base[i];
        sr += v.x; si += v.y;
        s2 = fmaf(v.x, v.x, s2); s2 = fmaf(v.y, v.y, s2);
    }
    __shared__ float red[3][256];
    red[0][threadIdx.x] = sr; red[1][threadIdx.x] = si; red[2][threadIdx.x] = s2;
    __syncthreads();
    for (int off = 128; off > 0; off >>= 1) {
        if (threadIdx.x < off) {
            red[0][threadIdx.x] += red[0][threadIdx.x + off];
            red[1][threadIdx.x] += red[1][threadIdx.x + off];
            red[2][threadIdx.x] += red[2][threadIdx.x + off];
        }
        __syncthreads();
    }
    if (threadIdx.x == 0) {
        float invN = 1.f / (float)Nel;
        float mur = red[0][0] * invN, mui = red[1][0] * invN;
        float var = red[2][0] * invN - mur * mur - mui * mui;
        float g = gamma[head * BB + b] * rsqrtf(var + 1e-5f);
        bn[head * BB + b] = make_float4(g, beta[head * BB + b] - mur * g, -mui * g, 0.f);
    }
}

// ---------------- init: irfft twiddle matrix, A-fragment order, split fp16 -----
// W[m][k2]: k2=2f -> scale_f*cos(2*pi*m*f/N); k2=2f+1 -> -scale_f*sin(...)
// W scaled by 2^10; S scaled by 2^5; epilogue multiplies by 2^-15.
// frag idx = ((mtile*KT + kt)*64 + lane)*8 + j ; m = mtile*16+(lane&15),
// k2 = kt*32 + (lane>>4)*8 + j.  sin(0)=0 zeroes DC/Nyquist imag (numpy irfft).
__global__ __launch_bounds__(256)
void init_w_kernel(u16* __restrict__ whi0, u16* __restrict__ wlo0,
                   u16* __restrict__ whi1, u16* __restrict__ wlo1) {
    int idx = blockIdx.x * 256 + threadIdx.x;
    int N, F, KT, id; u16 *dh, *dl;
    if (idx < 6144)              { N = 64;  F = F0n; KT = 3; dh = whi0; dl = wlo0; id = idx; }
    else if (idx < 6144 + 73728) { N = 256; F = F1n; KT = 9; dh = whi1; dl = wlo1; id = idx - 6144; }
    else return;
    int j    = id & 7;
    int lane = (id >> 3) & 63;
    int rest = id >> 9;
    int kt   = rest % KT;
    int mt   = rest / KT;
    int m  = mt * 16 + (lane & 15);
    int k2 = kt * 32 + (lane >> 4) * 8 + j;
    float v = 0.f;
    if (k2 < 2 * F) {
        int f = k2 >> 1;
        double scale = (f == 0 || f == F - 1) ? (1024.0 / N) : (2048.0 / N);
        int u = (m * f) % N;
        double th = 6.283185307179586476925286766559 * (double)u / (double)N;
        v = (float)((k2 & 1) ? (-scale * sin(th)) : (scale * cos(th)));
    }
    _Float16 h = (_Float16)v;
    _Float16 l = (_Float16)(v - (float)h);
    dh[id] = *(u16*)&h;
    dl[id] = *(u16*)&l;
}

// ---------------- init: fk tables repacked coalesced + per-(f,o) ci-sum --------
// fkq layout: [c2][f*32+o] float4 = (kr[2c2], ki[2c2], kr[2c2+1], ki[2c2+1])
//   -> einsum load at lane-consecutive i = f*32+o is fully coalesced (16B stride).
// fks layout: [f*32+o] float2 = sum_ci (kr, ki)  (folds the CBN beta/mu offset).
__global__ __launch_bounds__(256)
void init_fk_kernel(const float* __restrict__ r0, const float* __restrict__ i0,
                    const float* __restrict__ r1, const float* __restrict__ i1,
                    float4* __restrict__ q0, float4* __restrict__ q1,
                    float2* __restrict__ s0, float2* __restrict__ s1) {
    int idx = blockIdx.x * 256 + threadIdx.x;
    constexpr int NQ0 = 8 * F0n * 32;   // 8448
    constexpr int NQ1 = 8 * F1n * 32;   // 33024
    constexpr int NS0 = F0n * 32;       // 1056
    constexpr int NS1 = F1n * 32;       // 4128
    if (idx < NQ0) {
        int id = idx;
        int c2 = id / (F0n * 32); int rem = id % (F0n * 32);
        int f = rem >> 5, o = rem & 31;
        int s = (f * CIN + 2 * c2) * CO + o;
        q0[id] = make_float4(r0[s], i0[s], r0[s + CO], i0[s + CO]);
    } else if (idx < NQ0 + NQ1) {
        int id = idx - NQ0;
        int c2 = id / (F1n * 32); int rem = id % (F1n * 32);
        int f = rem >> 5, o = rem & 31;
        int s = (f * CIN + 2 * c2) * CO + o;
        q1[id] = make_float4(r1[s], i1[s], r1[s + CO], i1[s + CO]);
    } else if (idx < NQ0 + NQ1 + NS0) {
        int id = idx - NQ0 - NQ1;
        int f = id >> 5, o = id & 31;
        float sr = 0.f, si = 0.f;
        for (int ci = 0; ci < CIN; ++ci) {
            int s = (f * CIN + ci) * CO + o;
            sr += r0[s]; si += i0[s];
        }
        s0[id] = make_float2(sr, si);
    } else if (idx < NQ0 + NQ1 + NS0 + NS1) {
        int id = idx - NQ0 - NQ1 - NS0;
        int f = id >> 5, o = id & 31;
        float sr = 0.f, si = 0.f;
        for (int ci = 0; ci < CIN; ++ci) {
            int s = (f * CIN + ci) * CO + o;
            sr += r1[s]; si += i1[s];
        }
        s1[id] = make_float2(sr, si);
    }
}

// ---------------- fused CBN-apply + einsum(fp32) + irfft(split-fp16 MFMA) ------
// grid: B*(TFR+1); frame TFR re-uses spectrum of frame 0 (wrap frame)
// LDS: Shi/Slo only (37.9KB for N=256 -> 4 blocks/CU). The raw frame is staged
// into LDS overlaying the *Slo* region only; phase 2 writes Shi DIRECTLY
// (disjoint from the scratch, no race) and stashes only the Slo words in
// registers (17 u32 max) -> small live set, no launch_bounds VGPR cap needed.
// (Round-1 lesson: __launch_bounds__(256,4) forced VGPR=64 -> 2.6 GB of scratch
//  spill traffic per dispatch. Never cap below the live set.)
// CBN affine folded: S = g * sum_ci p (x) fk  +  (t_re + i t_im) (x) fksum.
template<int N, int F, int TFR, int CH0, int KT, int KPAD>
__global__ __launch_bounds__(256)
void istft_kernel(const float2* __restrict__ p,
                  const u16* __restrict__ whi, const u16* __restrict__ wlo,
                  const float4* __restrict__ fkq, const float2* __restrict__ fks,
                  const float4* __restrict__ bn,
                  const float* __restrict__ pbias, float* __restrict__ out) {
    constexpr int MTW = N / 64;            // M-tiles per wave (1 or 4)
    constexpr int FCO = F * CO;
    constexpr int QN  = (FCO + 255) / 256; // outputs per thread (stash size)
    __shared__ __align__(16) u16 smem[2][32][KPAD];
    auto& Shi = smem[0];                   // [o][k2] f16 hi (x32 scale)
    auto& Slo = smem[1];                   // [o][k2] f16 lo (residual)
    float2* xs = (float2*)&smem[1][0][0];  // scratch overlays Slo region only
    static_assert(CIN * F * 8 <= 32 * KPAD * 2, "scratch fits Slo");

    int t  = blockIdx.x % (TFR + 1);
    int b  = blockIdx.x / (TFR + 1);
    int tf = (t == TFR) ? 0 : t;
    float4 par = bn[(CH0 ? 1 : 0) * BB + b];   // (g, t_re, t_im, -)
    const float2* acc = p + ((size_t)b * TFR + tf) * CIN * F;

    // phase 1: coalesced raw-frame load into LDS scratch (Slo region)
    {
        const float4* a4 = (const float4*)acc;
        float4* x4 = (float4*)xs;
        for (int i = threadIdx.x; i < CIN * F / 2; i += 256) x4[i] = a4[i];
    }
    __syncthreads();

    // phase 2: einsum; hi-halves written straight to Shi (disjoint from xs),
    // lo-halves stashed in registers (static indices after unroll)
    uint32 rlo[QN];
    #pragma unroll
    for (int q = 0; q < QN; ++q) {
        int i = threadIdx.x + q * 256;
        if (i < FCO) {
            int f = i >> 5, o = i & 31;
            float re = 0.f, im = 0.f;
            #pragma unroll
            for (int c2 = 0; c2 < 8; ++c2) {
                float4 kk = fkq[c2 * FCO + i];          // coalesced (16B stride)
                float2 xa = xs[(2 * c2) * F + f];       // LDS broadcast
                float2 xb = xs[(2 * c2 + 1) * F + f];
                re = fmaf(xa.x, kk.x, re); re = fmaf(-xa.y, kk.y, re);
                im = fmaf(xa.x, kk.y, im); im = fmaf(xa.y, kk.x, im);
                re = fmaf(xb.x, kk.z, re); re = fmaf(-xb.y, kk.w, re);
                im = fmaf(xb.x, kk.w, im); im = fmaf(xb.y, kk.z, im);
            }
            float2 fv = fks[i];
            float res = fmaf(par.x, re, fmaf(par.y, fv.x, -par.z * fv.y)) * 32.f;
            float ims = fmaf(par.x, im, fmaf(par.y, fv.y,  par.z * fv.x)) * 32.f;
            _Float16 rh = (_Float16)res; _Float16 rl = (_Float16)(res - (float)rh);
            _Float16 ih = (_Float16)ims; _Float16 il = (_Float16)(ims - (float)ih);
            ((uint32*)&Shi[o][0])[f] = ((uint32)(*(u16*)&ih) << 16) | (uint32)(*(u16*)&rh);
            rlo[q] = ((uint32)(*(u16*)&il) << 16) | (uint32)(*(u16*)&rl);
        }
    }
    __syncthreads();                        // all xs reads done -> reuse as Slo

    // phase 3: spill lo stash to Slo + zero-pad K tail [F, KT*16) dwords
    #pragma unroll
    for (int q = 0; q < QN; ++q) {
        int i = threadIdx.x + q * 256;
        if (i < FCO) {
            int f = i >> 5, o = i & 31;
            ((uint32*)&Slo[o][0])[f] = rlo[q];
        }
    }
    for (int i = threadIdx.x; i < 32 * (KT * 16 - F); i += 256) {
        constexpr int cols = KT * 16 - F;
        int o = i / cols, j = i - o * cols;
        ((uint32*)&Shi[o][0])[F + j] = 0;
        ((uint32*)&Slo[o][0])[F + j] = 0;
    }
    __syncthreads();

    // phase 4: MFMA.  out[k][ch] = sum_k2 W[k][k2]*S[k2][ch],
    // W*S ~ Wh*Sh + Wh*Sl + Wl*Sh.  All W global loads batched per kt.
    int lane = threadIdx.x & 63, wave = threadIdx.x >> 6;
    int col = lane & 15, quad = lane >> 4;
    f32x4 accv[MTW][2];
    #pragma unroll
    for (int mt = 0; mt < MTW; ++mt)
        #pragma unroll
        for (int nt = 0; nt < 2; ++nt) {
            f32x4 z = {0.f, 0.f, 0.f, 0.f};
            accv[mt][nt] = z;
        }
    for (int kt = 0; kt < KT; ++kt) {
        half8 wah[MTW], wal[MTW];
        #pragma unroll
        for (int mt = 0; mt < MTW; ++mt) {
            int mtile = wave * MTW + mt;
            wah[mt] = ((const half8*)whi)[(mtile * KT + kt) * 64 + lane];
            wal[mt] = ((const half8*)wlo)[(mtile * KT + kt) * 64 + lane];
        }
        half8 bh0 = *(const half8*)&Shi[col][kt * 32 + quad * 8];
        half8 bh1 = *(const half8*)&Shi[16 + col][kt * 32 + quad * 8];
        half8 bl0 = *(const half8*)&Slo[col][kt * 32 + quad * 8];
        half8 bl1 = *(const half8*)&Slo[16 + col][kt * 32 + quad * 8];
        #pragma unroll
        for (int mt = 0; mt < MTW; ++mt) {
            accv[mt][0] = __builtin_amdgcn_mfma_f32_16x16x32_f16(wah[mt], bh0, accv[mt][0], 0, 0, 0);
            accv[mt][0] = __builtin_amdgcn_mfma_f32_16x16x32_f16(wah[mt], bl0, accv[mt][0], 0, 0, 0);
            accv[mt][0] = __builtin_amdgcn_mfma_f32_16x16x32_f16(wal[mt], bh0, accv[mt][0], 0, 0, 0);
            accv[mt][1] = __builtin_amdgcn_mfma_f32_16x16x32_f16(wah[mt], bh1, accv[mt][1], 0, 0, 0);
            accv[mt][1] = __builtin_amdgcn_mfma_f32_16x16x32_f16(wah[mt], bl1, accv[mt][1], 0, 0, 0);
            accv[mt][1] = __builtin_amdgcn_mfma_f32_16x16x32_f16(wal[mt], bh1, accv[mt][1], 0, 0, 0);
        }
    }
    // epilogue: row = quad*4+reg (4 consecutive l), col = ch within ntile
    constexpr float UNSCALE = 1.0f / 32768.0f;   // 2^-15 (W*2^10, S*2^5)
    size_t bb = (size_t)b * TCO;
    #pragma unroll
    for (int mt = 0; mt < MTW; ++mt) {
        int l0 = t * N + (wave * MTW + mt) * 16 + quad * 4 - N / 2;
        if ((unsigned)l0 < LL) {
            #pragma unroll
            for (int nt = 0; nt < 2; ++nt) {
                int ch = CH0 + nt * 16 + col;
                float pb = pbias[ch];
                f32x4 a = accv[mt][nt];
                float4 v;
                v.x = fmaxf(fmaf(a[0], UNSCALE, pb), 0.f);
                v.y = fmaxf(fmaf(a[1], UNSCALE, pb), 0.f);
                v.z = fmaxf(fmaf(a[2], UNSCALE, pb), 0.f);
                v.w = fmaxf(fmaf(a[3], UNSCALE, pb), 0.f);
                *(float4*)(out + (bb + ch) * LL + l0) = v;
            }
        }
    }
}

extern "C" void kernel_launch(void* const* d_in, const int* in_sizes, int n_in,
                              void* d_out, int out_size, void* d_ws, size_t ws_size,
                              hipStream_t stream) {
    const float* x     = (const float*)d_in[0];
    const float* gam   = (const float*)d_in[1];
    const float* bet   = (const float*)d_in[2];
    const float* mkr   = (const float*)d_in[3];
    const float* mki   = (const float*)d_in[4];
    const float* mbr   = (const float*)d_in[5];
    const float* mbi   = (const float*)d_in[6];
    const float* fk0r  = (const float*)d_in[7];
    const float* fk0i  = (const float*)d_in[8];
    const float* fk1r  = (const float*)d_in[9];
    const float* fk1i  = (const float*)d_in[10];
    const float* pbias = (const float*)d_in[11];
    float* out = (float*)d_out;

    float2* p0   = (float2*)d_ws;                                   // 34.6 MB
    float2* p1   = p0 + (size_t)BB * T0n * CIN * F0n;               // 33.8 MB
    float4* bnp  = (float4*)(p1 + (size_t)BB * T1n * CIN * F1n);    // 2 KB
    u16*    whi0 = (u16*)(bnp + 2 * BB);                            // 12 KB
    u16*    wlo0 = whi0 + 6144;
    u16*    whi1 = wlo0 + 6144;                                     // 144 KB
    u16*    wlo1 = whi1 + 73728;
    float4* fkq0 = (float4*)(wlo1 + 73728);                         // 132 KB
    float4* fkq1 = fkq0 + 8 * F0n * 32;                             // 516 KB
    float2* fks0 = (float2*)(fkq1 + 8 * F1n * 32);                  // 8 KB
    float2* fks1 = fks0 + F0n * 32;                                 // 33 KB

    init_w_kernel<<<(6144 + 73728 + 255) / 256, 256, 0, stream>>>(whi0, wlo0, whi1, wlo1);
    init_fk_kernel<<<(8 * (F0n + F1n) * 32 + (F0n + F1n) * 32 + 255) / 256, 256, 0, stream>>>(
        fk0r, fk0i, fk1r, fk1i, fkq0, fkq1, fks0, fks1);
    stft_kernel<64, 33, 8, 128><<<BB * CIN * 16, 256, 0, stream>>>(x, p0);
    stft_kernel<256, 129, 2, 32><<<BB * CIN * 16, 256, 0, stream>>>(x, p1);
    merge_kernel<<<(BB * T1n * CIN * F0n) / 256, 256, 0, stream>>>(p0, p1, mkr, mki, mbr, mbi);
    cbn_kernel<<<128, 256, 0, stream>>>(p0, p1, gam, bet, bnp);
    istft_kernel<64, 33, 128, 0, 3, 104><<<BB * (T0n + 1), 256, 0, stream>>>(
        p0, whi0, wlo0, fkq0, fks0, bnp, pbias, out);
    istft_kernel<256, 129, 32, 32, 9, 296><<<BB * (T1n + 1), 256, 0, stream>>>(
        p1, whi1, wlo1, fkq1, fks1, bnp, pbias, out);
}

// Round 3
// 451.872 us; speedup vs baseline: 3.1606x; 1.2549x over previous
//
#include <hip/hip_runtime.h>
#include <math.h>

// Problem constants
#define BB   64
#define CIN  16
#define LL   8192
#define CO   32
#define TCO  64
constexpr int T0n = 128;   // frames for n=64
constexpr int T1n = 32;    // frames for n=256
constexpr int F0n = 33;
constexpr int F1n = 129;

typedef unsigned int   uint32;
typedef unsigned short u16;
typedef __attribute__((ext_vector_type(8))) _Float16 half8;  // 8 f16 (4 VGPRs)
typedef __attribute__((ext_vector_type(4))) float    f32x4;  // MFMA accumulator

// ---------------- STFT as GEMM: spec[t][j] = sum_k X[t][k] * D[k][j] -----------
// X: frames (reflect-padded, non-overlapping in padded coords), split f16 hi/lo
// D[k][2f]=cos(2pi f k/N), D[k][2f+1]=-sin(2pi f k/N)  (rfft convention)
// Output j-interleaved re/im == existing float2 p layout viewed as float.
// Partitioning: cfg64 (M=128 tiles=8): waves split M, all 5 N-tiles.
//               cfg256 (M=32 tiles=2): waves split N-tiles (stride 4), both M.
template<int N, int F, int TFR, int NTILES, int KTT, int MT_W, int NT_W,
         int NT_STRIDE, bool MT_SPLIT>
__global__ __launch_bounds__(256)
void stft_mfma_kernel(const float* __restrict__ x,
                      const u16* __restrict__ dhi, const u16* __restrict__ dlo,
                      float* __restrict__ p) {
    constexpr int PADN = N + 8;            // +16B row pad -> 2-way LDS alias (free)
    __shared__ __align__(16) u16 Xhi[TFR * PADN];
    __shared__ __align__(16) u16 Xlo[TFR * PADN];
    int bc = blockIdx.x;                   // b*CIN + c
    const float* xrow = x + (size_t)bc * LL;

    // stage full row as frames [t][k], split fp16 (coalesced global, 2-way LDS)
    for (int i = threadIdx.x; i < TFR * N; i += 256) {
        int row = i / N, colk = i % N;     // N is power of two -> shifts
        int gi = i - N / 2;                // xp[i] = x[i - N/2], reflect left
        gi = gi < 0 ? -gi : gi;            // right pad never touched (last frame dropped)
        float v = xrow[gi];
        _Float16 h = (_Float16)v;
        _Float16 l = (_Float16)(v - (float)h);
        Xhi[row * PADN + colk] = *(u16*)&h;
        Xlo[row * PADN + colk] = *(u16*)&l;
    }
    __syncthreads();

    int lane = threadIdx.x & 63, w = threadIdx.x >> 6;
    int col = lane & 15, quad = lane >> 4;
    f32x4 acc[MT_W][NT_W];
    #pragma unroll
    for (int mi = 0; mi < MT_W; ++mi)
        #pragma unroll
        for (int nj = 0; nj < NT_W; ++nj) {
            f32x4 z = {0.f, 0.f, 0.f, 0.f};
            acc[mi][nj] = z;
        }

    for (int kt = 0; kt < KTT; ++kt) {
        half8 ah[MT_W], al[MT_W];
        #pragma unroll
        for (int mi = 0; mi < MT_W; ++mi) {
            int mt = MT_SPLIT ? (w * MT_W + mi) : mi;
            int t  = mt * 16 + col;
            const u16* base = &Xhi[t * PADN + kt * 32 + quad * 8];
            ah[mi] = *(const half8*)base;
            al[mi] = *(const half8*)&Xlo[t * PADN + kt * 32 + quad * 8];
        }
        #pragma unroll
        for (int nj = 0; nj < NT_W; ++nj) {
            int nt = MT_SPLIT ? nj : (w + nj * NT_STRIDE);
            if (nt < NTILES) {
                half8 bh = ((const half8*)dhi)[(nt * KTT + kt) * 64 + lane];
                half8 bl = ((const half8*)dlo)[(nt * KTT + kt) * 64 + lane];
                #pragma unroll
                for (int mi = 0; mi < MT_W; ++mi) {
                    acc[mi][nj] = __builtin_amdgcn_mfma_f32_16x16x32_f16(ah[mi], bh, acc[mi][nj], 0, 0, 0);
                    acc[mi][nj] = __builtin_amdgcn_mfma_f32_16x16x32_f16(ah[mi], bl, acc[mi][nj], 0, 0, 0);
                    acc[mi][nj] = __builtin_amdgcn_mfma_f32_16x16x32_f16(al[mi], bh, acc[mi][nj], 0, 0, 0);
                }
            }
        }
    }

    // store: C row (m-dim) = t within tile = quad*4+r, C col (n-dim) = j
    int b = bc / CIN, c = bc % CIN;
    #pragma unroll
    for (int mi = 0; mi < MT_W; ++mi) {
        int mt = MT_SPLIT ? (w * MT_W + mi) : mi;
        #pragma unroll
        for (int nj = 0; nj < NT_W; ++nj) {
            int nt = MT_SPLIT ? nj : (w + nj * NT_STRIDE);
            if (nt < NTILES) {
                int j = nt * 16 + col;
                if (j < 2 * F) {
                    int t0 = mt * 16 + quad * 4;
                    f32x4 a = acc[mi][nj];
                    #pragma unroll
                    for (int r = 0; r < 4; ++r) {
                        p[(((size_t)b * TFR + t0 + r) * CIN + c) * (2 * F) + j] = a[r];
                    }
                }
            }
        }
    }
}

// ---------------- init: STFT D tables, B-fragment order, split fp16 ------------
// frag idx = ((nt*KTT + kt)*64 + lane)*8 + jj ; j = nt*16+(lane&15),
// k = kt*32+(lane>>4)*8+jj.  D[k][2f]=cos, D[k][2f+1]=-sin; j>=2F -> 0.
__global__ __launch_bounds__(256)
void init_d_kernel(u16* __restrict__ dhi0, u16* __restrict__ dlo0,
                   u16* __restrict__ dhi1, u16* __restrict__ dlo1) {
    int idx = blockIdx.x * 256 + threadIdx.x;
    constexpr int SZ0 = 5 * 2 * 64 * 8;    // 5120
    constexpr int SZ1 = 17 * 8 * 64 * 8;   // 69632
    int N, F, KTT, id; u16 *dh, *dl;
    if (idx < SZ0)            { N = 64;  F = F0n; KTT = 2; dh = dhi0; dl = dlo0; id = idx; }
    else if (idx < SZ0 + SZ1) { N = 256; F = F1n; KTT = 8; dh = dhi1; dl = dlo1; id = idx - SZ0; }
    else return;
    int jj   = id & 7;
    int lane = (id >> 3) & 63;
    int rest = id >> 9;
    int kt   = rest % KTT;
    int nt   = rest / KTT;
    int j = nt * 16 + (lane & 15);
    int k = kt * 32 + (lane >> 4) * 8 + jj;
    float v = 0.f;
    if (j < 2 * F) {
        int f = j >> 1;
        int u = (f * k) % N;
        double th = 6.283185307179586476925286766559 * (double)u / (double)N;
        v = (float)((j & 1) ? -sin(th) : cos(th));
    }
    _Float16 h = (_Float16)v;
    _Float16 l = (_Float16)(v - (float)h);
    dh[id] = *(u16*)&h;
    dl[id] = *(u16*)&l;
}

// ---------------- merge (attention over 4 sub-frames), in-place into p1 --------
__global__ __launch_bounds__(256)
void merge_kernel(const float2* __restrict__ p0, float2* __restrict__ p1,
                  const float* __restrict__ mkr, const float* __restrict__ mki,
                  const float* __restrict__ mbr, const float* __restrict__ mbi) {
    int idx = blockIdx.x * 256 + threadIdx.x;
    const int total = BB * T1n * CIN * F0n;
    if (idx >= total) return;
    int f0 = idx % F0n; int r1 = idx / F0n;
    int c  = r1 % CIN;  int r2 = r1 / CIN;
    int t1 = r2 % T1n;  int b  = r2 / T1n;
    float2 pm[4];
    #pragma unroll
    for (int r = 0; r < 4; ++r) {
        int t = t1 * 4 + r;
        pm[r] = p0[(((size_t)b * T0n + t) * CIN + c) * F0n + f0];
    }
    float mag[4], mx = -1e30f;
    #pragma unroll
    for (int s = 0; s < 4; ++s) {
        float atr = mbr[s], ati = mbi[s];
        #pragma unroll
        for (int r = 0; r < 4; ++r) {
            float kr = mkr[r * 4 + s], ki = mki[r * 4 + s];
            atr = fmaf(pm[r].x, kr, atr); atr = fmaf(-pm[r].y, ki, atr);
            ati = fmaf(pm[r].x, ki, ati); ati = fmaf(pm[r].y, kr, ati);
        }
        mag[s] = sqrtf(atr * atr + ati * ati);
        mx = fmaxf(mx, mag[s]);
    }
    float se = 0.f;
    #pragma unroll
    for (int s = 0; s < 4; ++s) { mag[s] = expf(mag[s] - mx); se += mag[s]; }
    float inv = 4.0f / se;                 // RATIO / sum
    float mr = 0.f, mi = 0.f;
    #pragma unroll
    for (int r = 0; r < 4; ++r) { mr = fmaf(pm[r].x, mag[r], mr); mi = fmaf(pm[r].y, mag[r], mi); }
    p1[(((size_t)b * T1n + t1) * CIN + c) * F1n + 4 * f0] = make_float2(mr * inv, mi * inv);
}

// ---------------- complex batch-norm stats -> per-batch affine ------------------
__global__ __launch_bounds__(256)
void cbn_kernel(const float2* __restrict__ p0, const float2* __restrict__ p1,
                const float* __restrict__ gamma, const float* __restrict__ beta,
                float4* __restrict__ bn) {
    int head = blockIdx.x >> 6;
    int b    = blockIdx.x & 63;
    int Nel  = head ? (T1n * CIN * F1n) : (T0n * CIN * F0n);
    const float2* base = head ? (p1 + (size_t)b * (T1n * CIN * F1n))
                              : (p0 + (size_t)b * (T0n * CIN * F0n));
    float sr = 0.f, si = 0.f, s2 = 0.f;
    for (int i = threadIdx.x; i < Nel; i += 256) {
        float2 v = base[i];
        sr += v.x; si += v.y;
        s2 = fmaf(v.x, v.x, s2); s2 = fmaf(v.y, v.y, s2);
    }
    __shared__ float red[3][256];
    red[0][threadIdx.x] = sr; red[1][threadIdx.x] = si; red[2][threadIdx.x] = s2;
    __syncthreads();
    for (int off = 128; off > 0; off >>= 1) {
        if (threadIdx.x < off) {
            red[0][threadIdx.x] += red[0][threadIdx.x + off];
            red[1][threadIdx.x] += red[1][threadIdx.x + off];
            red[2][threadIdx.x] += red[2][threadIdx.x + off];
        }
        __syncthreads();
    }
    if (threadIdx.x == 0) {
        float invN = 1.f / (float)Nel;
        float mur = red[0][0] * invN, mui = red[1][0] * invN;
        float var = red[2][0] * invN - mur * mur - mui * mui;
        float g = gamma[head * BB + b] * rsqrtf(var + 1e-5f);
        bn[head * BB + b] = make_float4(g, beta[head * BB + b] - mur * g, -mui * g, 0.f);
    }
}

// ---------------- init: irfft twiddle matrix, A-fragment order, split fp16 -----
// W[m][k2]: k2=2f -> scale_f*cos(2*pi*m*f/N); k2=2f+1 -> -scale_f*sin(...)
// W scaled by 2^10; S scaled by 2^5; epilogue multiplies by 2^-15.
// frag idx = ((mtile*KT + kt)*64 + lane)*8 + j ; m = mtile*16+(lane&15),
// k2 = kt*32 + (lane>>4)*8 + j.  sin(0)=0 zeroes DC/Nyquist imag (numpy irfft).
__global__ __launch_bounds__(256)
void init_w_kernel(u16* __restrict__ whi0, u16* __restrict__ wlo0,
                   u16* __restrict__ whi1, u16* __restrict__ wlo1) {
    int idx = blockIdx.x * 256 + threadIdx.x;
    int N, F, KT, id; u16 *dh, *dl;
    if (idx < 6144)              { N = 64;  F = F0n; KT = 3; dh = whi0; dl = wlo0; id = idx; }
    else if (idx < 6144 + 73728) { N = 256; F = F1n; KT = 9; dh = whi1; dl = wlo1; id = idx - 6144; }
    else return;
    int j    = id & 7;
    int lane = (id >> 3) & 63;
    int rest = id >> 9;
    int kt   = rest % KT;
    int mt   = rest / KT;
    int m  = mt * 16 + (lane & 15);
    int k2 = kt * 32 + (lane >> 4) * 8 + j;
    float v = 0.f;
    if (k2 < 2 * F) {
        int f = k2 >> 1;
        double scale = (f == 0 || f == F - 1) ? (1024.0 / N) : (2048.0 / N);
        int u = (m * f) % N;
        double th = 6.283185307179586476925286766559 * (double)u / (double)N;
        v = (float)((k2 & 1) ? (-scale * sin(th)) : (scale * cos(th)));
    }
    _Float16 h = (_Float16)v;
    _Float16 l = (_Float16)(v - (float)h);
    dh[id] = *(u16*)&h;
    dl[id] = *(u16*)&l;
}

// ---------------- init: fk tables repacked coalesced + per-(f,o) ci-sum --------
// fkq layout: [c2][f*32+o] float4 = (kr[2c2], ki[2c2], kr[2c2+1], ki[2c2+1])
//   -> einsum load at lane-consecutive i = f*32+o is fully coalesced (16B stride).
// fks layout: [f*32+o] float2 = sum_ci (kr, ki)  (folds the CBN beta/mu offset).
__global__ __launch_bounds__(256)
void init_fk_kernel(const float* __restrict__ r0, const float* __restrict__ i0,
                    const float* __restrict__ r1, const float* __restrict__ i1,
                    float4* __restrict__ q0, float4* __restrict__ q1,
                    float2* __restrict__ s0, float2* __restrict__ s1) {
    int idx = blockIdx.x * 256 + threadIdx.x;
    constexpr int NQ0 = 8 * F0n * 32;   // 8448
    constexpr int NQ1 = 8 * F1n * 32;   // 33024
    constexpr int NS0 = F0n * 32;       // 1056
    constexpr int NS1 = F1n * 32;       // 4128
    if (idx < NQ0) {
        int id = idx;
        int c2 = id / (F0n * 32); int rem = id % (F0n * 32);
        int f = rem >> 5, o = rem & 31;
        int s = (f * CIN + 2 * c2) * CO + o;
        q0[id] = make_float4(r0[s], i0[s], r0[s + CO], i0[s + CO]);
    } else if (idx < NQ0 + NQ1) {
        int id = idx - NQ0;
        int c2 = id / (F1n * 32); int rem = id % (F1n * 32);
        int f = rem >> 5, o = rem & 31;
        int s = (f * CIN + 2 * c2) * CO + o;
        q1[id] = make_float4(r1[s], i1[s], r1[s + CO], i1[s + CO]);
    } else if (idx < NQ0 + NQ1 + NS0) {
        int id = idx - NQ0 - NQ1;
        int f = id >> 5, o = id & 31;
        float sr = 0.f, si = 0.f;
        for (int ci = 0; ci < CIN; ++ci) {
            int s = (f * CIN + ci) * CO + o;
            sr += r0[s]; si += i0[s];
        }
        s0[id] = make_float2(sr, si);
    } else if (idx < NQ0 + NQ1 + NS0 + NS1) {
        int id = idx - NQ0 - NQ1 - NS0;
        int f = id >> 5, o = id & 31;
        float sr = 0.f, si = 0.f;
        for (int ci = 0; ci < CIN; ++ci) {
            int s = (f * CIN + ci) * CO + o;
            sr += r1[s]; si += i1[s];
        }
        s1[id] = make_float2(sr, si);
    }
}

// ---------------- fused CBN-apply + einsum(fp32) + irfft(split-fp16 MFMA) ------
// grid: B*(TFR+1); frame TFR re-uses spectrum of frame 0 (wrap frame)
// LDS: Shi/Slo only; raw frame overlays the Slo region; phase 2 writes Shi
// directly and stashes only the lo-halves in registers (no VGPR cap -> no spill;
// round-1 lesson: __launch_bounds__(256,4) forced VGPR=64 -> 2.6 GB spill traffic).
// CBN affine folded: S = g * sum_ci p (x) fk  +  (t_re + i t_im) (x) fksum.
template<int N, int F, int TFR, int CH0, int KT, int KPAD>
__global__ __launch_bounds__(256)
void istft_kernel(const float2* __restrict__ p,
                  const u16* __restrict__ whi, const u16* __restrict__ wlo,
                  const float4* __restrict__ fkq, const float2* __restrict__ fks,
                  const float4* __restrict__ bn,
                  const float* __restrict__ pbias, float* __restrict__ out) {
    constexpr int MTW = N / 64;            // M-tiles per wave (1 or 4)
    constexpr int FCO = F * CO;
    constexpr int QN  = (FCO + 255) / 256; // outputs per thread (stash size)
    __shared__ __align__(16) u16 smem[2][32][KPAD];
    auto& Shi = smem[0];                   // [o][k2] f16 hi (x32 scale)
    auto& Slo = smem[1];                   // [o][k2] f16 lo (residual)
    float2* xs = (float2*)&smem[1][0][0];  // scratch overlays Slo region only
    static_assert(CIN * F * 8 <= 32 * KPAD * 2, "scratch fits Slo");

    int t  = blockIdx.x % (TFR + 1);
    int b  = blockIdx.x / (TFR + 1);
    int tf = (t == TFR) ? 0 : t;
    float4 par = bn[(CH0 ? 1 : 0) * BB + b];   // (g, t_re, t_im, -)
    const float2* acc = p + ((size_t)b * TFR + tf) * CIN * F;

    // phase 1: coalesced raw-frame load into LDS scratch (Slo region)
    {
        const float4* a4 = (const float4*)acc;
        float4* x4 = (float4*)xs;
        for (int i = threadIdx.x; i < CIN * F / 2; i += 256) x4[i] = a4[i];
    }
    __syncthreads();

    // phase 2: einsum; hi-halves written straight to Shi (disjoint from xs),
    // lo-halves stashed in registers (static indices after unroll)
    uint32 rlo[QN];
    #pragma unroll
    for (int q = 0; q < QN; ++q) {
        int i = threadIdx.x + q * 256;
        if (i < FCO) {
            int f = i >> 5, o = i & 31;
            float re = 0.f, im = 0.f;
            #pragma unroll
            for (int c2 = 0; c2 < 8; ++c2) {
                float4 kk = fkq[c2 * FCO + i];          // coalesced (16B stride)
                float2 xa = xs[(2 * c2) * F + f];       // LDS broadcast
                float2 xb = xs[(2 * c2 + 1) * F + f];
                re = fmaf(xa.x, kk.x, re); re = fmaf(-xa.y, kk.y, re);
                im = fmaf(xa.x, kk.y, im); im = fmaf(xa.y, kk.x, im);
                re = fmaf(xb.x, kk.z, re); re = fmaf(-xb.y, kk.w, re);
                im = fmaf(xb.x, kk.w, im); im = fmaf(xb.y, kk.z, im);
            }
            float2 fv = fks[i];
            float res = fmaf(par.x, re, fmaf(par.y, fv.x, -par.z * fv.y)) * 32.f;
            float ims = fmaf(par.x, im, fmaf(par.y, fv.y,  par.z * fv.x)) * 32.f;
            _Float16 rh = (_Float16)res; _Float16 rl = (_Float16)(res - (float)rh);
            _Float16 ih = (_Float16)ims; _Float16 il = (_Float16)(ims - (float)ih);
            ((uint32*)&Shi[o][0])[f] = ((uint32)(*(u16*)&ih) << 16) | (uint32)(*(u16*)&rh);
            rlo[q] = ((uint32)(*(u16*)&il) << 16) | (uint32)(*(u16*)&rl);
        }
    }
    __syncthreads();                        // all xs reads done -> reuse as Slo

    // phase 3: spill lo stash to Slo + zero-pad K tail [F, KT*16) dwords
    #pragma unroll
    for (int q = 0; q < QN; ++q) {
        int i = threadIdx.x + q * 256;
        if (i < FCO) {
            int f = i >> 5, o = i & 31;
            ((uint32*)&Slo[o][0])[f] = rlo[q];
        }
    }
    for (int i = threadIdx.x; i < 32 * (KT * 16 - F); i += 256) {
        constexpr int cols = KT * 16 - F;
        int o = i / cols, j = i - o * cols;
        ((uint32*)&Shi[o][0])[F + j] = 0;
        ((uint32*)&Slo[o][0])[F + j] = 0;
    }
    __syncthreads();

    // phase 4: MFMA.  out[k][ch] = sum_k2 W[k][k2]*S[k2][ch],
    // W*S ~ Wh*Sh + Wh*Sl + Wl*Sh.  All W global loads batched per kt.
    int lane = threadIdx.x & 63, wave = threadIdx.x >> 6;
    int col = lane & 15, quad = lane >> 4;
    f32x4 accv[MTW][2];
    #pragma unroll
    for (int mt = 0; mt < MTW; ++mt)
        #pragma unroll
        for (int nt = 0; nt < 2; ++nt) {
            f32x4 z = {0.f, 0.f, 0.f, 0.f};
            accv[mt][nt] = z;
        }
    for (int kt = 0; kt < KT; ++kt) {
        half8 wah[MTW], wal[MTW];
        #pragma unroll
        for (int mt = 0; mt < MTW; ++mt) {
            int mtile = wave * MTW + mt;
            wah[mt] = ((const half8*)whi)[(mtile * KT + kt) * 64 + lane];
            wal[mt] = ((const half8*)wlo)[(mtile * KT + kt) * 64 + lane];
        }
        half8 bh0 = *(const half8*)&Shi[col][kt * 32 + quad * 8];
        half8 bh1 = *(const half8*)&Shi[16 + col][kt * 32 + quad * 8];
        half8 bl0 = *(const half8*)&Slo[col][kt * 32 + quad * 8];
        half8 bl1 = *(const half8*)&Slo[16 + col][kt * 32 + quad * 8];
        #pragma unroll
        for (int mt = 0; mt < MTW; ++mt) {
            accv[mt][0] = __builtin_amdgcn_mfma_f32_16x16x32_f16(wah[mt], bh0, accv[mt][0], 0, 0, 0);
            accv[mt][0] = __builtin_amdgcn_mfma_f32_16x16x32_f16(wah[mt], bl0, accv[mt][0], 0, 0, 0);
            accv[mt][0] = __builtin_amdgcn_mfma_f32_16x16x32_f16(wal[mt], bh0, accv[mt][0], 0, 0, 0);
            accv[mt][1] = __builtin_amdgcn_mfma_f32_16x16x32_f16(wah[mt], bh1, accv[mt][1], 0, 0, 0);
            accv[mt][1] = __builtin_amdgcn_mfma_f32_16x16x32_f16(wah[mt], bl1, accv[mt][1], 0, 0, 0);
            accv[mt][1] = __builtin_amdgcn_mfma_f32_16x16x32_f16(wal[mt], bh1, accv[mt][1], 0, 0, 0);
        }
    }
    // epilogue: row = quad*4+reg (4 consecutive l), col = ch within ntile
    constexpr float UNSCALE = 1.0f / 32768.0f;   // 2^-15 (W*2^10, S*2^5)
    size_t bb = (size_t)b * TCO;
    #pragma unroll
    for (int mt = 0; mt < MTW; ++mt) {
        int l0 = t * N + (wave * MTW + mt) * 16 + quad * 4 - N / 2;
        if ((unsigned)l0 < LL) {
            #pragma unroll
            for (int nt = 0; nt < 2; ++nt) {
                int ch = CH0 + nt * 16 + col;
                float pb = pbias[ch];
                f32x4 a = accv[mt][nt];
                float4 v;
                v.x = fmaxf(fmaf(a[0], UNSCALE, pb), 0.f);
                v.y = fmaxf(fmaf(a[1], UNSCALE, pb), 0.f);
                v.z = fmaxf(fmaf(a[2], UNSCALE, pb), 0.f);
                v.w = fmaxf(fmaf(a[3], UNSCALE, pb), 0.f);
                *(float4*)(out + (bb + ch) * LL + l0) = v;
            }
        }
    }
}

extern "C" void kernel_launch(void* const* d_in, const int* in_sizes, int n_in,
                              void* d_out, int out_size, void* d_ws, size_t ws_size,
                              hipStream_t stream) {
    const float* x     = (const float*)d_in[0];
    const float* gam   = (const float*)d_in[1];
    const float* bet   = (const float*)d_in[2];
    const float* mkr   = (const float*)d_in[3];
    const float* mki   = (const float*)d_in[4];
    const float* mbr   = (const float*)d_in[5];
    const float* mbi   = (const float*)d_in[6];
    const float* fk0r  = (const float*)d_in[7];
    const float* fk0i  = (const float*)d_in[8];
    const float* fk1r  = (const float*)d_in[9];
    const float* fk1i  = (const float*)d_in[10];
    const float* pbias = (const float*)d_in[11];
    float* out = (float*)d_out;

    float2* p0   = (float2*)d_ws;                                   // 34.6 MB
    float2* p1   = p0 + (size_t)BB * T0n * CIN * F0n;               // 33.8 MB
    float4* bnp  = (float4*)(p1 + (size_t)BB * T1n * CIN * F1n);    // 2 KB
    u16*    whi0 = (u16*)(bnp + 2 * BB);                            // 12 KB
    u16*    wlo0 = whi0 + 6144;
    u16*    whi1 = wlo0 + 6144;                                     // 144 KB
    u16*    wlo1 = whi1 + 73728;
    float4* fkq0 = (float4*)(wlo1 + 73728);                         // 132 KB
    float4* fkq1 = fkq0 + 8 * F0n * 32;                             // 516 KB
    float2* fks0 = (float2*)(fkq1 + 8 * F1n * 32);                  // 8 KB
    float2* fks1 = fks0 + F0n * 32;                                 // 33 KB
    u16*    dhi0 = (u16*)(fks1 + F1n * 32);                         // 10 KB
    u16*    dlo0 = dhi0 + 5120;                                     // 10 KB
    u16*    dhi1 = dlo0 + 5120;                                     // 139 KB
    u16*    dlo1 = dhi1 + 69632;                                    // 139 KB

    init_w_kernel<<<(6144 + 73728 + 255) / 256, 256, 0, stream>>>(whi0, wlo0, whi1, wlo1);
    init_d_kernel<<<(5120 + 69632 + 255) / 256, 256, 0, stream>>>(dhi0, dlo0, dhi1, dlo1);
    init_fk_kernel<<<(8 * (F0n + F1n) * 32 + (F0n + F1n) * 32 + 255) / 256, 256, 0, stream>>>(
        fk0r, fk0i, fk1r, fk1i, fkq0, fkq1, fks0, fks1);
    // cfg64:  M=128 (8 tiles, waves split M), N-tiles=5, K=64  (2 ksteps)
    stft_mfma_kernel<64, F0n, 128, 5, 2, 2, 5, 1, true><<<BB * CIN, 256, 0, stream>>>(
        x, dhi0, dlo0, (float*)p0);
    // cfg256: M=32 (2 tiles, both per wave), N-tiles=17 (waves stride 4), K=256 (8 ksteps)
    stft_mfma_kernel<256, F1n, 32, 17, 8, 2, 5, 4, false><<<BB * CIN, 256, 0, stream>>>(
        x, dhi1, dlo1, (float*)p1);
    merge_kernel<<<(BB * T1n * CIN * F0n) / 256, 256, 0, stream>>>(p0, p1, mkr, mki, mbr, mbi);
    cbn_kernel<<<128, 256, 0, stream>>>(p0, p1, gam, bet, bnp);
    istft_kernel<64, 33, 128, 0, 3, 104><<<BB * (T0n + 1), 256, 0, stream>>>(
        p0, whi0, wlo0, fkq0, fks0, bnp, pbias, out);
    istft_kernel<256, 129, 32, 32, 9, 296><<<BB * (T1n + 1), 256, 0, stream>>>(
        p1, whi1, wlo1, fkq1, fks1, bnp, pbias, out);
}